// Round 2
// baseline (2187.399 us; speedup 1.0000x reference)
//
#include <hip/hip_runtime.h>

#define DIM 128
#define BN_EPS 1e-5f

// ---------------- CSR build ----------------

__global__ __launch_bounds__(256) void k_count(const int* __restrict__ dst,
                                               int* __restrict__ ideg, int ne) {
  int stride = gridDim.x * blockDim.x;
  for (int e = blockIdx.x * blockDim.x + threadIdx.x; e < ne; e += stride)
    atomicAdd(&ideg[dst[e]], 1);
}

// single-block exclusive scan over n degrees -> off[0..n], also copies to cur
__global__ __launch_bounds__(1024) void k_scan(const int* __restrict__ ideg,
                                               int* __restrict__ off,
                                               int* __restrict__ cur, int n) {
  __shared__ int sums[1024];
  int t = threadIdx.x;
  int chunk = (n + 1023) >> 10;
  int s0 = t * chunk;
  int s1 = s0 + chunk;
  if (s0 > n) s0 = n;
  if (s1 > n) s1 = n;
  int tot = 0;
  for (int i = s0; i < s1; ++i) tot += ideg[i];
  sums[t] = tot;
  __syncthreads();
  for (int d = 1; d < 1024; d <<= 1) {
    int v = (t >= d) ? sums[t - d] : 0;
    __syncthreads();
    sums[t] += v;
    __syncthreads();
  }
  int run = (t == 0) ? 0 : sums[t - 1];
  for (int i = s0; i < s1; ++i) {
    off[i] = run;
    cur[i] = run;
    run += ideg[i];
  }
  if (t == 1023) off[n] = run;
}

__global__ __launch_bounds__(256) void k_dinv(const int* __restrict__ ideg,
                                              float* __restrict__ dinv, int n) {
  int i = blockIdx.x * blockDim.x + threadIdx.x;
  if (i < n) dinv[i] = rsqrtf((float)ideg[i] + 1.0f);  // +1 = self loop
}

__global__ __launch_bounds__(256) void k_fill(const int* __restrict__ src,
                                              const int* __restrict__ dst,
                                              int* __restrict__ cur,
                                              int* __restrict__ csr_src,
                                              float* __restrict__ csr_w,
                                              const float* __restrict__ dinv, int ne) {
  int stride = gridDim.x * blockDim.x;
  for (int e = blockIdx.x * blockDim.x + threadIdx.x; e < ne; e += stride) {
    int d = dst[e];
    int s = src[e];
    int p = atomicAdd(&cur[d], 1);
    csr_src[p] = s;
    csr_w[p] = dinv[s];
  }
}

// ---------------- GEMM: C[n,128] = A[n,128] @ W[128,128] ----------------

__global__ __launch_bounds__(256) void k_gemm(const float* __restrict__ A,
                                              const float* __restrict__ W,
                                              float* __restrict__ C, int n) {
  __shared__ float sW[DIM][DIM];
  __shared__ float sH[DIM][DIM];
  int tid = threadIdx.x;
  int row0 = blockIdx.x * DIM;

  {
    const float4* Wv = (const float4*)W;
    float4* sWv = (float4*)&sW[0][0];
    for (int i = tid; i < DIM * DIM / 4; i += 256) sWv[i] = Wv[i];
  }
  {
    float4* sHv = (float4*)&sH[0][0];
    for (int i = tid; i < DIM * DIM / 4; i += 256) {
      int r = i >> 5;
      int gr = row0 + r;
      float4 v = make_float4(0.f, 0.f, 0.f, 0.f);
      if (gr < n) v = ((const float4*)A)[(size_t)gr * (DIM / 4) + (i & 31)];
      sHv[i] = v;
    }
  }
  __syncthreads();

  int tx = tid & 15;
  int ty = tid >> 4;
  int c0 = tx * 8;
  int r0 = ty * 8;
  float acc[8][8];
#pragma unroll
  for (int i = 0; i < 8; ++i)
#pragma unroll
    for (int j = 0; j < 8; ++j) acc[i][j] = 0.f;

  for (int k = 0; k < DIM; ++k) {
    float4 b0 = *(const float4*)&sW[k][c0];
    float4 b1 = *(const float4*)&sW[k][c0 + 4];
    float b[8] = {b0.x, b0.y, b0.z, b0.w, b1.x, b1.y, b1.z, b1.w};
    float a[8];
#pragma unroll
    for (int i = 0; i < 8; ++i) a[i] = sH[r0 + i][k];
#pragma unroll
    for (int i = 0; i < 8; ++i)
#pragma unroll
      for (int j = 0; j < 8; ++j) acc[i][j] = fmaf(a[i], b[j], acc[i][j]);
  }

#pragma unroll
  for (int i = 0; i < 8; ++i) {
    int gr = row0 + r0 + i;
    if (gr < n) {
      float4 v0 = make_float4(acc[i][0], acc[i][1], acc[i][2], acc[i][3]);
      float4 v1 = make_float4(acc[i][4], acc[i][5], acc[i][6], acc[i][7]);
      float4* cp = (float4*)&C[(size_t)gr * DIM + c0];
      cp[0] = v0;
      cp[1] = v1;
    }
  }
}

// ---------------- Aggregation + bias + residual + BN partial stats ----------------

__global__ __launch_bounds__(256) void k_agg(const float* __restrict__ xw,
                                             const int* __restrict__ off,
                                             const int* __restrict__ csr_src,
                                             const float* __restrict__ csr_w,
                                             const float* __restrict__ dinv,
                                             const float* __restrict__ bias,
                                             const float* __restrict__ prev,
                                             float* __restrict__ out,
                                             float* __restrict__ ssum,
                                             float* __restrict__ ssq, int n) {
  int tid = threadIdx.x;
  int c = tid & (DIM - 1);
  int half = tid >> 7;
  float bc = bias[c];
  float lsum = 0.f, lsq = 0.f;

  for (int node = blockIdx.x * 2 + half; node < n; node += gridDim.x * 2) {
    int e0 = off[node];
    int e1 = off[node + 1];
    float di = dinv[node];
    float acc = di * xw[(size_t)node * DIM + c];
    for (int e = e0; e < e1; ++e) {
      int s = csr_src[e];
      float w = csr_w[e];
      acc = fmaf(w, xw[(size_t)s * DIM + c], acc);
    }
    float v = fmaf(di, acc, bc);
    if (prev) v += prev[(size_t)node * DIM + c];
    out[(size_t)node * DIM + c] = v;
    lsum += v;
    lsq = fmaf(v, v, lsq);
  }

  __shared__ float red[256];
  red[tid] = lsum;
  __syncthreads();
  if (half == 0) atomicAdd(&ssum[c], red[tid] + red[tid + 128]);
  __syncthreads();
  red[tid] = lsq;
  __syncthreads();
  if (half == 0) atomicAdd(&ssq[c], red[tid] + red[tid + 128]);
}

// ---------------- BN finalize + normalize/relu ----------------

__global__ void k_bn(const float* __restrict__ ssum, const float* __restrict__ ssq,
                     const float* __restrict__ gamma, const float* __restrict__ beta,
                     float* __restrict__ scale, float* __restrict__ shift, float invn) {
  int c = threadIdx.x;
  float mu = ssum[c] * invn;
  float var = ssq[c] * invn - mu * mu;
  float rstd = rsqrtf(var + BN_EPS);
  float sc = rstd * gamma[c];
  scale[c] = sc;
  shift[c] = beta[c] - mu * sc;
}

__global__ __launch_bounds__(256) void k_norm(float* __restrict__ out,
                                              const float* __restrict__ scale,
                                              const float* __restrict__ shift, int n4) {
  int stride = gridDim.x * blockDim.x;
  for (int i = blockIdx.x * blockDim.x + threadIdx.x; i < n4; i += stride) {
    int cg = i & 31;
    float4 sc = ((const float4*)scale)[cg];
    float4 sh = ((const float4*)shift)[cg];
    float4 v = ((float4*)out)[i];
    v.x = fmaxf(fmaf(v.x, sc.x, sh.x), 0.f);
    v.y = fmaxf(fmaf(v.y, sc.y, sh.y), 0.f);
    v.z = fmaxf(fmaf(v.z, sc.z, sh.z), 0.f);
    v.w = fmaxf(fmaf(v.w, sc.w, sh.w), 0.f);
    ((float4*)out)[i] = v;
  }
}

// ---------------- launch ----------------

extern "C" void kernel_launch(void* const* d_in, const int* in_sizes, int n_in,
                              void* d_out, int out_size, void* d_ws, size_t ws_size,
                              hipStream_t stream) {
  const float* x = (const float*)d_in[0];
  const int* ei = (const int*)d_in[1];
  int n = in_sizes[0] / DIM;   // 100000
  int ne = in_sizes[1] / 2;    // 1600000
  const int* src = ei;
  const int* dst = ei + ne;

  const float *W[3], *B[3], *G[3], *Bt[3];
  if (n_in >= 14) {
    for (int l = 0; l < 3; ++l) {
      W[l] = (const float*)d_in[2 + l];
      B[l] = (const float*)d_in[5 + l];
      G[l] = (const float*)d_in[8 + l];
      Bt[l] = (const float*)d_in[11 + l];
    }
  } else {  // tuples flattened into concatenated arrays
    for (int l = 0; l < 3; ++l) {
      W[l] = (const float*)d_in[2] + (size_t)l * DIM * DIM;
      B[l] = (const float*)d_in[3] + (size_t)l * DIM;
      G[l] = (const float*)d_in[4] + (size_t)l * DIM;
      Bt[l] = (const float*)d_in[5] + (size_t)l * DIM;
    }
  }

  float* out = (float*)d_out;

  char* p = (char*)d_ws;
  auto carve = [&](size_t bytes) {
    void* q = (void*)p;
    p += (bytes + 255) & ~(size_t)255;
    return q;
  };
  int* ideg = (int*)carve((size_t)n * 4);
  int* coff = (int*)carve((size_t)(n + 1) * 4);
  int* cur = (int*)carve((size_t)n * 4);
  float* dinv = (float*)carve((size_t)n * 4);
  int* csr_src = (int*)carve((size_t)ne * 4);
  float* csr_w = (float*)carve((size_t)ne * 4);
  float* xw = (float*)carve((size_t)n * DIM * 4);
  float* buf1 = (float*)carve((size_t)n * DIM * 4);
  float* stats = (float*)carve(3 * 256 * 4);
  float* scsh = (float*)carve(256 * 4);

  hipMemsetAsync(ideg, 0, (size_t)n * 4, stream);
  hipMemsetAsync(stats, 0, 3 * 256 * 4, stream);

  k_count<<<1024, 256, 0, stream>>>(dst, ideg, ne);
  k_scan<<<1, 1024, 0, stream>>>(ideg, coff, cur, n);
  k_dinv<<<(n + 255) / 256, 256, 0, stream>>>(ideg, dinv, n);
  k_fill<<<1024, 256, 0, stream>>>(src, dst, cur, csr_src, csr_w, dinv, ne);

  const float* hin = x;
  const float* prev = nullptr;
  for (int l = 0; l < 3; ++l) {
    float* ho = (l == 1) ? buf1 : out;
    k_gemm<<<(n + DIM - 1) / DIM, 256, 0, stream>>>(hin, W[l], xw, n);
    float* ss = stats + l * 256;
    float* sq = ss + 128;
    k_agg<<<1024, 256, 0, stream>>>(xw, coff, csr_src, csr_w, dinv, B[l], prev, ho, ss, sq, n);
    k_bn<<<1, 128, 0, stream>>>(ss, sq, G[l], Bt[l], scsh, scsh + 128, 1.0f / (float)n);
    k_norm<<<2048, 256, 0, stream>>>(ho, scsh, scsh + 128, n * DIM / 4);
    prev = ho;
    hin = ho;
  }
}

// Round 3
// 1672.226 us; speedup vs baseline: 1.3081x; 1.3081x over previous
//
#include <hip/hip_runtime.h>

#define DIM 128
#define BN_EPS 1e-5f

// ---------------- CSR build ----------------

__global__ __launch_bounds__(256) void k_count(const int* __restrict__ dst,
                                               int* __restrict__ ideg, int ne) {
  int stride = gridDim.x * blockDim.x;
  for (int e = blockIdx.x * blockDim.x + threadIdx.x; e < ne; e += stride)
    atomicAdd(&ideg[dst[e]], 1);
}

// single-block exclusive scan over n degrees -> off[0..n], also copies to cur
__global__ __launch_bounds__(1024) void k_scan(const int* __restrict__ ideg,
                                               int* __restrict__ off,
                                               int* __restrict__ cur, int n) {
  __shared__ int sums[1024];
  int t = threadIdx.x;
  int chunk = (n + 1023) >> 10;
  int s0 = t * chunk;
  int s1 = s0 + chunk;
  if (s0 > n) s0 = n;
  if (s1 > n) s1 = n;
  int tot = 0;
  for (int i = s0; i < s1; ++i) tot += ideg[i];
  sums[t] = tot;
  __syncthreads();
  for (int d = 1; d < 1024; d <<= 1) {
    int v = (t >= d) ? sums[t - d] : 0;
    __syncthreads();
    sums[t] += v;
    __syncthreads();
  }
  int run = (t == 0) ? 0 : sums[t - 1];
  for (int i = s0; i < s1; ++i) {
    off[i] = run;
    cur[i] = run;
    run += ideg[i];
  }
  if (t == 1023) off[n] = run;
}

__global__ __launch_bounds__(256) void k_dinv(const int* __restrict__ ideg,
                                              float* __restrict__ dinv, int n) {
  int i = blockIdx.x * blockDim.x + threadIdx.x;
  if (i < n) dinv[i] = rsqrtf((float)ideg[i] + 1.0f);  // +1 = self loop
}

__global__ __launch_bounds__(256) void k_fill(const int* __restrict__ src,
                                              const int* __restrict__ dst,
                                              int* __restrict__ cur,
                                              int* __restrict__ csr_src, int ne) {
  int stride = gridDim.x * blockDim.x;
  for (int e = blockIdx.x * blockDim.x + threadIdx.x; e < ne; e += stride) {
    int d = dst[e];
    int s = src[e];
    int p = atomicAdd(&cur[d], 1);
    csr_src[p] = s;
  }
}

// ---------------- GEMM: C[n,128] = dinv[row] * (A[n,128] @ W[128,128]) ----------------

__global__ __launch_bounds__(256) void k_gemm(const float* __restrict__ A,
                                              const float* __restrict__ W,
                                              const float* __restrict__ dinv,
                                              float* __restrict__ C, int n) {
  __shared__ float sW[DIM][DIM];
  __shared__ float sH[DIM][DIM];
  int tid = threadIdx.x;
  int row0 = blockIdx.x * DIM;

  {
    const float4* Wv = (const float4*)W;
    float4* sWv = (float4*)&sW[0][0];
    for (int i = tid; i < DIM * DIM / 4; i += 256) sWv[i] = Wv[i];
  }
  {
    float4* sHv = (float4*)&sH[0][0];
    for (int i = tid; i < DIM * DIM / 4; i += 256) {
      int r = i >> 5;
      int gr = row0 + r;
      float4 v = make_float4(0.f, 0.f, 0.f, 0.f);
      if (gr < n) v = ((const float4*)A)[(size_t)gr * (DIM / 4) + (i & 31)];
      sHv[i] = v;
    }
  }
  __syncthreads();

  int tx = tid & 15;
  int ty = tid >> 4;
  int c0 = tx * 8;
  int r0 = ty * 8;
  float acc[8][8];
#pragma unroll
  for (int i = 0; i < 8; ++i)
#pragma unroll
    for (int j = 0; j < 8; ++j) acc[i][j] = 0.f;

  for (int k = 0; k < DIM; ++k) {
    float4 b0 = *(const float4*)&sW[k][c0];
    float4 b1 = *(const float4*)&sW[k][c0 + 4];
    float b[8] = {b0.x, b0.y, b0.z, b0.w, b1.x, b1.y, b1.z, b1.w};
    float a[8];
#pragma unroll
    for (int i = 0; i < 8; ++i) a[i] = sH[r0 + i][k];
#pragma unroll
    for (int i = 0; i < 8; ++i)
#pragma unroll
      for (int j = 0; j < 8; ++j) acc[i][j] = fmaf(a[i], b[j], acc[i][j]);
  }

#pragma unroll
  for (int i = 0; i < 8; ++i) {
    int gr = row0 + r0 + i;
    if (gr < n) {
      float di = dinv[gr];
      float4 v0 = make_float4(di * acc[i][0], di * acc[i][1], di * acc[i][2], di * acc[i][3]);
      float4 v1 = make_float4(di * acc[i][4], di * acc[i][5], di * acc[i][6], di * acc[i][7]);
      float4* cp = (float4*)&C[(size_t)gr * DIM + c0];
      cp[0] = v0;
      cp[1] = v1;
    }
  }
}

// ---------------- Aggregation + bias + residual + BN partial stats ----------------
// xw rows are pre-scaled by dinv[row]. 32 threads per node, float4 per thread.

__global__ __launch_bounds__(256) void k_agg(const float* __restrict__ xw,
                                             const int* __restrict__ off,
                                             const int* __restrict__ csr_src,
                                             const float* __restrict__ dinv,
                                             const float* __restrict__ bias,
                                             const float* __restrict__ prev,
                                             float* __restrict__ out,
                                             float* __restrict__ ssum,
                                             float* __restrict__ ssq, int n) {
  int tid = threadIdx.x;
  int lane = tid & 31;  // column group: cols [lane*4, lane*4+4)
  int grp = tid >> 5;   // 8 node slots per block
  const float4* xw4 = (const float4*)xw;
  float4 bc = ((const float4*)bias)[lane];
  float4 lsum = make_float4(0.f, 0.f, 0.f, 0.f);
  float4 lsq = make_float4(0.f, 0.f, 0.f, 0.f);

  for (int node = blockIdx.x * 8 + grp; node < n; node += gridDim.x * 8) {
    int e0 = off[node];
    int e1 = off[node + 1];
    float4 acc = xw4[(size_t)node * 32 + lane];  // self loop (pre-scaled)
    int e = e0;
    for (; e + 4 <= e1; e += 4) {
      int s0 = csr_src[e];
      int s1 = csr_src[e + 1];
      int s2 = csr_src[e + 2];
      int s3 = csr_src[e + 3];
      float4 a = xw4[(size_t)s0 * 32 + lane];
      float4 b = xw4[(size_t)s1 * 32 + lane];
      float4 c = xw4[(size_t)s2 * 32 + lane];
      float4 d = xw4[(size_t)s3 * 32 + lane];
      acc.x += (a.x + b.x) + (c.x + d.x);
      acc.y += (a.y + b.y) + (c.y + d.y);
      acc.z += (a.z + b.z) + (c.z + d.z);
      acc.w += (a.w + b.w) + (c.w + d.w);
    }
    for (; e < e1; ++e) {
      float4 a = xw4[(size_t)csr_src[e] * 32 + lane];
      acc.x += a.x;
      acc.y += a.y;
      acc.z += a.z;
      acc.w += a.w;
    }
    float di = dinv[node];
    float4 v;
    v.x = fmaf(di, acc.x, bc.x);
    v.y = fmaf(di, acc.y, bc.y);
    v.z = fmaf(di, acc.z, bc.z);
    v.w = fmaf(di, acc.w, bc.w);
    if (prev) {
      float4 pv = ((const float4*)prev)[(size_t)node * 32 + lane];
      v.x += pv.x;
      v.y += pv.y;
      v.z += pv.z;
      v.w += pv.w;
    }
    ((float4*)out)[(size_t)node * 32 + lane] = v;
    lsum.x += v.x;
    lsum.y += v.y;
    lsum.z += v.z;
    lsum.w += v.w;
    lsq.x = fmaf(v.x, v.x, lsq.x);
    lsq.y = fmaf(v.y, v.y, lsq.y);
    lsq.z = fmaf(v.z, v.z, lsq.z);
    lsq.w = fmaf(v.w, v.w, lsq.w);
  }

  __shared__ float4 red[256];
  red[tid] = lsum;
  __syncthreads();
  if (grp == 0) {
    float4 s = red[lane];
#pragma unroll
    for (int g = 1; g < 8; ++g) {
      float4 t = red[g * 32 + lane];
      s.x += t.x;
      s.y += t.y;
      s.z += t.z;
      s.w += t.w;
    }
    atomicAdd(&ssum[lane * 4 + 0], s.x);
    atomicAdd(&ssum[lane * 4 + 1], s.y);
    atomicAdd(&ssum[lane * 4 + 2], s.z);
    atomicAdd(&ssum[lane * 4 + 3], s.w);
  }
  __syncthreads();
  red[tid] = lsq;
  __syncthreads();
  if (grp == 0) {
    float4 s = red[lane];
#pragma unroll
    for (int g = 1; g < 8; ++g) {
      float4 t = red[g * 32 + lane];
      s.x += t.x;
      s.y += t.y;
      s.z += t.z;
      s.w += t.w;
    }
    atomicAdd(&ssq[lane * 4 + 0], s.x);
    atomicAdd(&ssq[lane * 4 + 1], s.y);
    atomicAdd(&ssq[lane * 4 + 2], s.z);
    atomicAdd(&ssq[lane * 4 + 3], s.w);
  }
}

// ---------------- BN finalize + normalize/relu ----------------

__global__ void k_bn(const float* __restrict__ ssum, const float* __restrict__ ssq,
                     const float* __restrict__ gamma, const float* __restrict__ beta,
                     float* __restrict__ scale, float* __restrict__ shift, float invn) {
  int c = threadIdx.x;
  float mu = ssum[c] * invn;
  float var = ssq[c] * invn - mu * mu;
  float rstd = rsqrtf(var + BN_EPS);
  float sc = rstd * gamma[c];
  scale[c] = sc;
  shift[c] = beta[c] - mu * sc;
}

__global__ __launch_bounds__(256) void k_norm(float* __restrict__ out,
                                              const float* __restrict__ scale,
                                              const float* __restrict__ shift, int n4) {
  int stride = gridDim.x * blockDim.x;
  for (int i = blockIdx.x * blockDim.x + threadIdx.x; i < n4; i += stride) {
    int cg = i & 31;
    float4 sc = ((const float4*)scale)[cg];
    float4 sh = ((const float4*)shift)[cg];
    float4 v = ((float4*)out)[i];
    v.x = fmaxf(fmaf(v.x, sc.x, sh.x), 0.f);
    v.y = fmaxf(fmaf(v.y, sc.y, sh.y), 0.f);
    v.z = fmaxf(fmaf(v.z, sc.z, sh.z), 0.f);
    v.w = fmaxf(fmaf(v.w, sc.w, sh.w), 0.f);
    ((float4*)out)[i] = v;
  }
}

// ---------------- launch ----------------

extern "C" void kernel_launch(void* const* d_in, const int* in_sizes, int n_in,
                              void* d_out, int out_size, void* d_ws, size_t ws_size,
                              hipStream_t stream) {
  const float* x = (const float*)d_in[0];
  const int* ei = (const int*)d_in[1];
  int n = in_sizes[0] / DIM;   // 100000
  int ne = in_sizes[1] / 2;    // 1600000
  const int* src = ei;
  const int* dst = ei + ne;

  const float *W[3], *B[3], *G[3], *Bt[3];
  if (n_in >= 14) {
    for (int l = 0; l < 3; ++l) {
      W[l] = (const float*)d_in[2 + l];
      B[l] = (const float*)d_in[5 + l];
      G[l] = (const float*)d_in[8 + l];
      Bt[l] = (const float*)d_in[11 + l];
    }
  } else {  // tuples flattened into concatenated arrays
    for (int l = 0; l < 3; ++l) {
      W[l] = (const float*)d_in[2] + (size_t)l * DIM * DIM;
      B[l] = (const float*)d_in[3] + (size_t)l * DIM;
      G[l] = (const float*)d_in[4] + (size_t)l * DIM;
      Bt[l] = (const float*)d_in[5] + (size_t)l * DIM;
    }
  }

  float* out = (float*)d_out;

  char* p = (char*)d_ws;
  auto carve = [&](size_t bytes) {
    void* q = (void*)p;
    p += (bytes + 255) & ~(size_t)255;
    return q;
  };
  int* ideg = (int*)carve((size_t)n * 4);
  int* coff = (int*)carve((size_t)(n + 1) * 4);
  int* cur = (int*)carve((size_t)n * 4);
  float* dinv = (float*)carve((size_t)n * 4);
  int* csr_src = (int*)carve((size_t)ne * 4);
  float* xw = (float*)carve((size_t)n * DIM * 4);
  float* buf1 = (float*)carve((size_t)n * DIM * 4);
  float* stats = (float*)carve(3 * 256 * 4);
  float* scsh = (float*)carve(256 * 4);

  hipMemsetAsync(ideg, 0, (size_t)n * 4, stream);
  hipMemsetAsync(stats, 0, 3 * 256 * 4, stream);

  k_count<<<1024, 256, 0, stream>>>(dst, ideg, ne);
  k_scan<<<1, 1024, 0, stream>>>(ideg, coff, cur, n);
  k_dinv<<<(n + 255) / 256, 256, 0, stream>>>(ideg, dinv, n);
  k_fill<<<1024, 256, 0, stream>>>(src, dst, cur, csr_src, ne);

  const float* hin = x;
  const float* prev = nullptr;
  for (int l = 0; l < 3; ++l) {
    float* ho = (l == 1) ? buf1 : out;
    k_gemm<<<(n + DIM - 1) / DIM, 256, 0, stream>>>(hin, W[l], dinv, xw, n);
    float* ss = stats + l * 256;
    float* sq = ss + 128;
    k_agg<<<2048, 256, 0, stream>>>(xw, coff, csr_src, dinv, B[l], prev, ho, ss, sq, n);
    k_bn<<<1, 128, 0, stream>>>(ss, sq, G[l], Bt[l], scsh, scsh + 128, 1.0f / (float)n);
    k_norm<<<2048, 256, 0, stream>>>(ho, scsh, scsh + 128, n * DIM / 4);
    prev = ho;
    hin = ho;
  }
}